// Round 1
// baseline (1522.501 us; speedup 1.0000x reference)
//
#include <hip/hip_runtime.h>
#include <cstdint>
#include <cstddef>

static constexpr int kNS = 100000;
static constexpr int kNC = 512;
static constexpr int kES = 3200000;
static constexpr int kEC = 16384;

// ---------------- CSR build ----------------
__global__ void k_hist(const int* __restrict__ col, int E, int* __restrict__ cnt) {
  int i = blockIdx.x * blockDim.x + threadIdx.x;
  if (i < E) atomicAdd(&cnt[col[i]], 1);
}

__global__ void k_dis(const int* __restrict__ cnt, int N, float* __restrict__ dis) {
  int i = blockIdx.x * blockDim.x + threadIdx.x;
  if (i < N) dis[i] = rsqrtf((float)(cnt[i] + 1));  // +1 = self loop
}

__global__ void k_scan1(const int* __restrict__ cnt, int N, int* __restrict__ starts, int* __restrict__ bsum) {
  __shared__ int s[256];
  int t = threadIdx.x;
  int i = blockIdx.x * 256 + t;
  int v = (i < N) ? cnt[i] : 0;
  s[t] = v;
  __syncthreads();
  for (int o = 1; o < 256; o <<= 1) {
    int x = (t >= o) ? s[t - o] : 0;
    __syncthreads();
    s[t] += x;
    __syncthreads();
  }
  if (i < N) starts[i] = s[t] - v;  // exclusive within block
  if (t == 255) bsum[blockIdx.x] = s[255];
}

__global__ void k_scan2(int* __restrict__ bsum, int nb) {
  __shared__ int s[256];
  int t = threadIdx.x;
  int run = 0;
  for (int base = 0; base < nb; base += 256) {
    int i = base + t;
    int v = (i < nb) ? bsum[i] : 0;
    s[t] = v;
    __syncthreads();
    for (int o = 1; o < 256; o <<= 1) {
      int x = (t >= o) ? s[t - o] : 0;
      __syncthreads();
      s[t] += x;
      __syncthreads();
    }
    if (i < nb) bsum[i] = run + s[t] - v;
    int tot = s[255];
    __syncthreads();
    run += tot;
  }
}

__global__ void k_scan3(int* __restrict__ starts, int* __restrict__ cursor, const int* __restrict__ bsum, int N) {
  int i = blockIdx.x * 256 + threadIdx.x;
  if (i < N) {
    int v = starts[i] + bsum[blockIdx.x];
    starts[i] = v;
    cursor[i] = v;
  }
}

__global__ void k_scatter(const int* __restrict__ row, const int* __restrict__ col, int E,
                          int* __restrict__ cursor, int* __restrict__ srow) {
  int i = blockIdx.x * blockDim.x + threadIdx.x;
  if (i < E) {
    int pos = atomicAdd(&cursor[col[i]], 1);
    srow[pos] = row[i];
  }
}

// ---------------- GCN linear layers (pre-scaled by dis[row]) ----------------
// hs[N,64] = (x[N,7] @ W[7,64]) * dis[row]
__global__ __launch_bounds__(256) void k_lin7(const float* __restrict__ x, const float* __restrict__ W,
                                              const float* __restrict__ dis, float* __restrict__ hs, int N) {
  __shared__ float Ws[7 * 64];
  int t = threadIdx.x;
  for (int j = t; j < 7 * 64; j += 256) Ws[j] = W[j];
  __syncthreads();
  int idx = blockIdx.x * 256 + t;
  if (idx < N * 64) {
    int r = idx >> 6, c = idx & 63;
    const float* xr = x + (size_t)r * 7;
    float a = 0.f;
#pragma unroll
    for (int k = 0; k < 7; k++) a = fmaf(xr[k], Ws[k * 64 + c], a);
    hs[idx] = a * dis[r];
  }
}

// hs[N,128] = (xin[N,64] @ W[64,128]) * dis[row]   (8 rows per block)
__global__ __launch_bounds__(256) void k_lin64x128(const float* __restrict__ xin, const float* __restrict__ W,
                                                   const float* __restrict__ dis, float* __restrict__ hs, int N) {
  __shared__ float Ws[64 * 128];
  __shared__ float xs[8][64];
  int t = threadIdx.x;
  for (int j = t; j < 64 * 128; j += 256) Ws[j] = W[j];
  int r0 = blockIdx.x * 8;
  for (int j = t; j < 8 * 64; j += 256) {
    int r = j >> 6, k = j & 63;
    int gr = r0 + r;
    xs[r][k] = (gr < N) ? xin[(size_t)gr * 64 + k] : 0.f;
  }
  __syncthreads();
  int c = t & 127;
  int rb = (t >> 7) * 4;
  float acc[4] = {0.f, 0.f, 0.f, 0.f};
  for (int k = 0; k < 64; k++) {
    float w = Ws[k * 128 + c];
#pragma unroll
    for (int rr = 0; rr < 4; rr++) acc[rr] = fmaf(xs[rb + rr][k], w, acc[rr]);
  }
#pragma unroll
  for (int rr = 0; rr < 4; rr++) {
    int gr = r0 + rb + rr;
    if (gr < N) hs[(size_t)gr * 128 + c] = acc[rr] * dis[gr];
  }
}

// ---------------- aggregation: out[c] = relu(dis[c]*(hs[c]+sum_{r->c} hs[r]) + b) ----------------
template <int F>
__global__ void k_agg(const float* __restrict__ hs, const int* __restrict__ starts, const int* __restrict__ cnt,
                      const int* __restrict__ srow, const float* __restrict__ dis, const float* __restrict__ b,
                      float* __restrict__ out, int N) {
  int c = blockIdx.x;
  if (c >= N) return;
  int t = threadIdx.x;
  float acc = hs[(size_t)c * F + t];  // self loop (hs already has dis[c] factor)
  int s0 = starts[c], n = cnt[c];
  const int* sp = srow + s0;
  for (int e = 0; e < n; e++) {
    int r = sp[e];
    acc += hs[(size_t)r * F + t];
  }
  out[(size_t)c * F + t] = fmaxf(fmaf(dis[c], acc, b[t]), 0.f);
}

// ---------------- GEMM1: xcdec[M,128] = Q[M,512] @ xc[512,128]  (fp32 tiled) ----------------
__global__ __launch_bounds__(256) void k_gemm_q(const float* __restrict__ Q, const float* __restrict__ xc,
                                                float* __restrict__ out, int M) {
  __shared__ float As[16][64];
  __shared__ float Bs[16][128];
  int tid = threadIdx.x;
  int m0 = blockIdx.x * 64;
  int tm = tid >> 5;  // 0..7
  int tn = tid & 31;  // 0..31
  float acc[8][4];
#pragma unroll
  for (int r = 0; r < 8; r++)
#pragma unroll
    for (int c = 0; c < 4; c++) acc[r][c] = 0.f;

  int lm = tid >> 2;        // 0..63
  int lk = (tid & 3) * 4;   // 0,4,8,12
  const bool arow_ok = (m0 + lm) < M;
  const float* aptr = Q + (size_t)(m0 + lm) * 512 + lk;

  for (int k0 = 0; k0 < 512; k0 += 16) {
    float4 av = arow_ok ? *(const float4*)(aptr + k0) : float4{0.f, 0.f, 0.f, 0.f};
#pragma unroll
    for (int j = 0; j < 2; j++) {
      int li = tid * 2 + j;
      int kk = li >> 5;
      int c4 = (li & 31) << 2;
      *(float4*)&Bs[kk][c4] = *(const float4*)(xc + (size_t)(k0 + kk) * 128 + c4);
    }
    As[lk + 0][lm] = av.x;
    As[lk + 1][lm] = av.y;
    As[lk + 2][lm] = av.z;
    As[lk + 3][lm] = av.w;
    __syncthreads();
#pragma unroll
    for (int kk = 0; kk < 16; kk++) {
      float4 a0 = *(const float4*)&As[kk][tm * 8];
      float4 a1 = *(const float4*)&As[kk][tm * 8 + 4];
      float4 b = *(const float4*)&Bs[kk][tn * 4];
      float ar[8] = {a0.x, a0.y, a0.z, a0.w, a1.x, a1.y, a1.z, a1.w};
      float bc[4] = {b.x, b.y, b.z, b.w};
#pragma unroll
      for (int r = 0; r < 8; r++)
#pragma unroll
        for (int c = 0; c < 4; c++) acc[r][c] = fmaf(ar[r], bc[c], acc[r][c]);
    }
    __syncthreads();
  }
#pragma unroll
  for (int r = 0; r < 8; r++) {
    int gm = m0 + tm * 8 + r;
    if (gm < M) {
      float4 v = {acc[r][0], acc[r][1], acc[r][2], acc[r][3]};
      *(float4*)(out + (size_t)gm * 128 + tn * 4) = v;
    }
  }
}

// ---------------- GEMM2 + gate: fused = w0*xs + w1*xcdec, w = softmax(relu(concat@A1+ab1)@A2+ab2) ----------------
__global__ __launch_bounds__(256) void k_gemm_fuse(const float* __restrict__ xs, const float* __restrict__ xcd,
                                                   const float* __restrict__ A1, const float* __restrict__ ab1,
                                                   const float* __restrict__ A2, const float* __restrict__ ab2,
                                                   float* __restrict__ fused_out, int M) {
  __shared__ float As[16][64];
  __shared__ float Bs[16][128];
  int tid = threadIdx.x;
  int m0 = blockIdx.x * 64;
  int tm = tid >> 5;
  int tn = tid & 31;
  float acc[8][4];
#pragma unroll
  for (int r = 0; r < 8; r++)
#pragma unroll
    for (int c = 0; c < 4; c++) acc[r][c] = 0.f;

  int lm = tid >> 2;
  int lk = (tid & 3) * 4;
  const bool arow_ok = (m0 + lm) < M;

  for (int k0 = 0; k0 < 256; k0 += 16) {
    const float* src = (k0 < 128) ? xs : xcd;
    int kb = (k0 < 128) ? k0 : (k0 - 128);
    float4 av = arow_ok ? *(const float4*)(src + (size_t)(m0 + lm) * 128 + kb + lk)
                        : float4{0.f, 0.f, 0.f, 0.f};
#pragma unroll
    for (int j = 0; j < 2; j++) {
      int li = tid * 2 + j;
      int kk = li >> 5;
      int c4 = (li & 31) << 2;
      *(float4*)&Bs[kk][c4] = *(const float4*)(A1 + (size_t)(k0 + kk) * 128 + c4);
    }
    As[lk + 0][lm] = av.x;
    As[lk + 1][lm] = av.y;
    As[lk + 2][lm] = av.z;
    As[lk + 3][lm] = av.w;
    __syncthreads();
#pragma unroll
    for (int kk = 0; kk < 16; kk++) {
      float4 a0 = *(const float4*)&As[kk][tm * 8];
      float4 a1 = *(const float4*)&As[kk][tm * 8 + 4];
      float4 b = *(const float4*)&Bs[kk][tn * 4];
      float ar[8] = {a0.x, a0.y, a0.z, a0.w, a1.x, a1.y, a1.z, a1.w};
      float bc[4] = {b.x, b.y, b.z, b.w};
#pragma unroll
      for (int r = 0; r < 8; r++)
#pragma unroll
        for (int c = 0; c < 4; c++) acc[r][c] = fmaf(ar[r], bc[c], acc[r][c]);
    }
    __syncthreads();
  }

  // epilogue: T = relu(acc + ab1); u = T@A2 + ab2; softmax; fused
  float bb[4], a20[4], a21[4];
#pragma unroll
  for (int c = 0; c < 4; c++) {
    int col = tn * 4 + c;
    bb[c] = ab1[col];
    a20[c] = A2[col * 2 + 0];
    a21[c] = A2[col * 2 + 1];
  }
  float u0[8], u1[8];
#pragma unroll
  for (int r = 0; r < 8; r++) {
    float s0 = 0.f, s1 = 0.f;
#pragma unroll
    for (int c = 0; c < 4; c++) {
      float tv = fmaxf(acc[r][c] + bb[c], 0.f);
      s0 = fmaf(tv, a20[c], s0);
      s1 = fmaf(tv, a21[c], s1);
    }
    u0[r] = s0;
    u1[r] = s1;
  }
#pragma unroll
  for (int off = 1; off < 32; off <<= 1) {
#pragma unroll
    for (int r = 0; r < 8; r++) {
      u0[r] += __shfl_xor(u0[r], off);
      u1[r] += __shfl_xor(u1[r], off);
    }
  }
  float b20 = ab2[0], b21 = ab2[1];
#pragma unroll
  for (int r = 0; r < 8; r++) {
    int gm = m0 + tm * 8 + r;
    if (gm < M) {
      float ua = u0[r] + b20, ub = u1[r] + b21;
      float mx = fmaxf(ua, ub);
      float e0 = __expf(ua - mx), e1 = __expf(ub - mx);
      float inv = 1.f / (e0 + e1);
      float w0 = e0 * inv, w1 = e1 * inv;
      float4 vx = *(const float4*)(xs + (size_t)gm * 128 + tn * 4);
      float4 vc = *(const float4*)(xcd + (size_t)gm * 128 + tn * 4);
      float4 o;
      o.x = w0 * vx.x + w1 * vc.x;
      o.y = w0 * vx.y + w1 * vc.y;
      o.z = w0 * vx.z + w1 * vc.z;
      o.w = w0 * vx.w + w1 * vc.w;
      *(float4*)(fused_out + (size_t)gm * 128 + tn * 4) = o;
    }
  }
}

// ---------------- heads: class = fused@Wcls+bcls ; dom = relu(fused@D1+db1)@D2+db2 ----------------
__global__ __launch_bounds__(256) void k_final(const float* __restrict__ fused, const float* __restrict__ Wcls,
                                               const float* __restrict__ bcls, const float* __restrict__ D1,
                                               const float* __restrict__ db1, const float* __restrict__ D2,
                                               const float* __restrict__ db2, float* __restrict__ cls_out,
                                               float* __restrict__ dom_out, int M) {
  __shared__ float D1s[128 * 64];
  __shared__ float Ws[128 * 9];
  __shared__ float D2s[64 * 2];
  __shared__ float fr[16][128];
  __shared__ float hh[16][64];
  int t = threadIdx.x;
  for (int j = t; j < 128 * 64; j += 256) D1s[j] = D1[j];
  for (int j = t; j < 128 * 9; j += 256) Ws[j] = Wcls[j];
  if (t < 128) D2s[t] = D2[t];
  int r0 = blockIdx.x * 16;
  for (int j = t; j < 16 * 128; j += 256) {
    int r = j >> 7, k = j & 127;
    int gr = r0 + r;
    fr[r][k] = (gr < M) ? fused[(size_t)gr * 128 + k] : 0.f;
  }
  __syncthreads();
  // domain hidden: 16x64
#pragma unroll
  for (int q = 0; q < 4; q++) {
    int j = t + q * 256;
    int r = j >> 6, h = j & 63;
    float a = db1[h];
    for (int k = 0; k < 128; k++) a = fmaf(fr[r][k], D1s[k * 64 + h], a);
    hh[r][h] = fmaxf(a, 0.f);
  }
  // class: 16x9
  if (t < 144) {
    int r = t / 9, c = t % 9;
    float a = bcls[c];
    for (int k = 0; k < 128; k++) a = fmaf(fr[r][k], Ws[k * 9 + c], a);
    int gr = r0 + r;
    if (gr < M) cls_out[(size_t)gr * 9 + c] = a;
  }
  __syncthreads();
  // domain out: 16x2
  if (t < 32) {
    int r = t >> 1, j = t & 1;
    float a = db2[j];
    for (int h = 0; h < 64; h++) a = fmaf(hh[r][h], D2s[h * 2 + j], a);
    int gr = r0 + r;
    if (gr < M) dom_out[(size_t)gr * 2 + j] = a;
  }
}

extern "C" void kernel_launch(void* const* d_in, const int* in_sizes, int n_in,
                              void* d_out, int out_size, void* d_ws, size_t ws_size,
                              hipStream_t stream) {
  const float* x_s = (const float*)d_in[0];
  const float* x_c = (const float*)d_in[1];
  const float* Q = (const float*)d_in[2];
  const int* eis = (const int*)d_in[3];
  const int* eic = (const int*)d_in[4];
  const float* W1s = (const float*)d_in[5];
  const float* b1s = (const float*)d_in[6];
  const float* W2s = (const float*)d_in[7];
  const float* b2s = (const float*)d_in[8];
  const float* W1c = (const float*)d_in[9];
  const float* b1c = (const float*)d_in[10];
  const float* W2c = (const float*)d_in[11];
  const float* b2c = (const float*)d_in[12];
  const float* A1 = (const float*)d_in[13];
  const float* ab1 = (const float*)d_in[14];
  const float* A2 = (const float*)d_in[15];
  const float* ab2 = (const float*)d_in[16];
  const float* Wcls = (const float*)d_in[17];
  const float* bcls = (const float*)d_in[18];
  const float* D1 = (const float*)d_in[19];
  const float* db1 = (const float*)d_in[20];
  const float* D2 = (const float*)d_in[21];
  const float* db2 = (const float*)d_in[22];

  float* out_cls = (float*)d_out;                  // [NS,9]
  float* out_dom = out_cls + (size_t)kNS * 9;      // [NS,2]
  float* out_fus = out_dom + (size_t)kNS * 2;      // [NS,128]

  char* p = (char*)d_ws;
  auto alloc = [&](size_t bytes) -> void* {
    void* r = (void*)p;
    p += (bytes + 255) & ~(size_t)255;
    return r;
  };
  int* deg_s = (int*)alloc((size_t)kNS * 4);
  int* starts_s = (int*)alloc((size_t)kNS * 4);
  int* cursor_s = (int*)alloc((size_t)kNS * 4);
  int* bsum_s = (int*)alloc(512 * 4);
  float* dis_s = (float*)alloc((size_t)kNS * 4);
  int* srow_s = (int*)alloc((size_t)kES * 4);
  int* deg_c = (int*)alloc((size_t)kNC * 4);
  int* starts_c = (int*)alloc((size_t)kNC * 4);
  int* cursor_c = (int*)alloc((size_t)kNC * 4);
  int* bsum_c = (int*)alloc(512 * 4);
  float* dis_c = (float*)alloc((size_t)kNC * 4);
  int* srow_c = (int*)alloc((size_t)kEC * 4);
  float* hc1 = (float*)alloc((size_t)kNC * 64 * 4);
  float* xc1 = (float*)alloc((size_t)kNC * 64 * 4);
  float* hc2 = (float*)alloc((size_t)kNC * 128 * 4);
  float* xc2 = (float*)alloc((size_t)kNC * 128 * 4);
  float* R1 = (float*)alloc((size_t)kNS * 128 * 4);  // hs1 / hs2 / xcdec
  float* R2 = (float*)alloc((size_t)kNS * 64 * 4);   // xs1
  float* R3 = (float*)alloc((size_t)kNS * 128 * 4);  // xs2
  (void)ws_size;
  (void)in_sizes;
  (void)n_in;
  (void)out_size;

  hipMemsetAsync(deg_s, 0, (size_t)kNS * 4, stream);
  hipMemsetAsync(deg_c, 0, (size_t)kNC * 4, stream);

  const int nbS = (kNS + 255) / 256;
  const int nbC = (kNC + 255) / 256;

  // sample-graph CSR
  k_hist<<<(kES + 255) / 256, 256, 0, stream>>>(eis + kES, kES, deg_s);
  k_dis<<<nbS, 256, 0, stream>>>(deg_s, kNS, dis_s);
  k_scan1<<<nbS, 256, 0, stream>>>(deg_s, kNS, starts_s, bsum_s);
  k_scan2<<<1, 256, 0, stream>>>(bsum_s, nbS);
  k_scan3<<<nbS, 256, 0, stream>>>(starts_s, cursor_s, bsum_s, kNS);
  k_scatter<<<(kES + 255) / 256, 256, 0, stream>>>(eis, eis + kES, kES, cursor_s, srow_s);

  // cluster-graph CSR
  k_hist<<<(kEC + 255) / 256, 256, 0, stream>>>(eic + kEC, kEC, deg_c);
  k_dis<<<nbC, 256, 0, stream>>>(deg_c, kNC, dis_c);
  k_scan1<<<nbC, 256, 0, stream>>>(deg_c, kNC, starts_c, bsum_c);
  k_scan2<<<1, 256, 0, stream>>>(bsum_c, nbC);
  k_scan3<<<nbC, 256, 0, stream>>>(starts_c, cursor_c, bsum_c, kNC);
  k_scatter<<<(kEC + 255) / 256, 256, 0, stream>>>(eic, eic + kEC, kEC, cursor_c, srow_c);

  // cluster branch
  k_lin7<<<(kNC * 64 + 255) / 256, 256, 0, stream>>>(x_c, W1c, dis_c, hc1, kNC);
  k_agg<64><<<kNC, 64, 0, stream>>>(hc1, starts_c, deg_c, srow_c, dis_c, b1c, xc1, kNC);
  k_lin64x128<<<(kNC + 7) / 8, 256, 0, stream>>>(xc1, W2c, dis_c, hc2, kNC);
  k_agg<128><<<kNC, 128, 0, stream>>>(hc2, starts_c, deg_c, srow_c, dis_c, b2c, xc2, kNC);

  // sample branch
  k_lin7<<<(kNS * 64 + 255) / 256, 256, 0, stream>>>(x_s, W1s, dis_s, R1, kNS);
  k_agg<64><<<kNS, 64, 0, stream>>>(R1, starts_s, deg_s, srow_s, dis_s, b1s, R2, kNS);
  k_lin64x128<<<(kNS + 7) / 8, 256, 0, stream>>>(R2, W2s, dis_s, R1, kNS);
  k_agg<128><<<kNS, 128, 0, stream>>>(R1, starts_s, deg_s, srow_s, dis_s, b2s, R3, kNS);

  // decode + fusion gate + heads
  k_gemm_q<<<(kNS + 63) / 64, 256, 0, stream>>>(Q, xc2, R1, kNS);  // xcdec -> R1
  k_gemm_fuse<<<(kNS + 63) / 64, 256, 0, stream>>>(R3, R1, A1, ab1, A2, ab2, out_fus, kNS);
  k_final<<<(kNS + 15) / 16, 256, 0, stream>>>(out_fus, Wcls, bcls, D1, db1, D2, db2, out_cls, out_dom, kNS);
}

// Round 2
// 1093.595 us; speedup vs baseline: 1.3922x; 1.3922x over previous
//
#include <hip/hip_runtime.h>
#include <cstdint>
#include <cstddef>

static constexpr int kNS = 100000;
static constexpr int kNC = 512;
static constexpr int kES = 3200000;
static constexpr int kEC = 16384;

typedef __attribute__((ext_vector_type(8))) short short8;
typedef __attribute__((ext_vector_type(4))) float f32x4;

__device__ __forceinline__ unsigned short f2bf(float f) {
  union { float f; unsigned u; } v; v.f = f;
  unsigned u = v.u;
  unsigned r = (u + 0x7fffu + ((u >> 16) & 1u)) >> 16;
  return (unsigned short)r;
}
__device__ __forceinline__ float bflo(unsigned v) { return __uint_as_float(v << 16); }
__device__ __forceinline__ float bfhi(unsigned v) { return __uint_as_float(v & 0xffff0000u); }
__device__ __forceinline__ float bf2f(unsigned short s) { return __uint_as_float(((unsigned)s) << 16); }

// ---------------- CSR build ----------------
__global__ void k_hist(const int* __restrict__ col, int E, int* __restrict__ cnt) {
  int i = blockIdx.x * blockDim.x + threadIdx.x;
  if (i < E) atomicAdd(&cnt[col[i]], 1);
}

__global__ void k_dis(const int* __restrict__ cnt, int N, float* __restrict__ dis) {
  int i = blockIdx.x * blockDim.x + threadIdx.x;
  if (i < N) dis[i] = rsqrtf((float)(cnt[i] + 1));  // +1 = self loop
}

__global__ void k_scan1(const int* __restrict__ cnt, int N, int* __restrict__ starts, int* __restrict__ bsum) {
  __shared__ int s[256];
  int t = threadIdx.x;
  int i = blockIdx.x * 256 + t;
  int v = (i < N) ? cnt[i] : 0;
  s[t] = v;
  __syncthreads();
  for (int o = 1; o < 256; o <<= 1) {
    int x = (t >= o) ? s[t - o] : 0;
    __syncthreads();
    s[t] += x;
    __syncthreads();
  }
  if (i < N) starts[i] = s[t] - v;
  if (t == 255) bsum[blockIdx.x] = s[255];
}

__global__ void k_scan2(int* __restrict__ bsum, int nb) {
  __shared__ int s[256];
  int t = threadIdx.x;
  int run = 0;
  for (int base = 0; base < nb; base += 256) {
    int i = base + t;
    int v = (i < nb) ? bsum[i] : 0;
    s[t] = v;
    __syncthreads();
    for (int o = 1; o < 256; o <<= 1) {
      int x = (t >= o) ? s[t - o] : 0;
      __syncthreads();
      s[t] += x;
      __syncthreads();
    }
    if (i < nb) bsum[i] = run + s[t] - v;
    int tot = s[255];
    __syncthreads();
    run += tot;
  }
}

__global__ void k_scan3(int* __restrict__ starts, int* __restrict__ cursor, const int* __restrict__ bsum, int N) {
  int i = blockIdx.x * 256 + threadIdx.x;
  if (i < N) {
    int v = starts[i] + bsum[blockIdx.x];
    starts[i] = v;
    cursor[i] = v;
  }
}

__global__ void k_scatter(const int* __restrict__ row, const int* __restrict__ col, int E,
                          int* __restrict__ cursor, int* __restrict__ srow) {
  int i = blockIdx.x * blockDim.x + threadIdx.x;
  if (i < E) {
    int pos = atomicAdd(&cursor[col[i]], 1);
    srow[pos] = row[i];
  }
}

// ---------------- layer-1 linear: hs[N,64](bf16) = (x[N,7] @ W[7,64]) * dis[row] ----------------
__global__ __launch_bounds__(256) void k_lin7(const float* __restrict__ x, const float* __restrict__ W,
                                              const float* __restrict__ dis, unsigned short* __restrict__ hs, int N) {
  __shared__ float Ws[7 * 64];
  int t = threadIdx.x;
  for (int j = t; j < 7 * 64; j += 256) Ws[j] = W[j];
  __syncthreads();
  int idx = blockIdx.x * 256 + t;
  if (idx < N * 32) {
    int r = idx >> 5, c2 = (idx & 31) * 2;
    const float* xr = x + (size_t)r * 7;
    float a0 = 0.f, a1 = 0.f;
#pragma unroll
    for (int k = 0; k < 7; k++) {
      float xv = xr[k];
      a0 = fmaf(xv, Ws[k * 64 + c2], a0);
      a1 = fmaf(xv, Ws[k * 64 + c2 + 1], a1);
    }
    float d = dis[r];
    unsigned pk = (unsigned)f2bf(a0 * d) | ((unsigned)f2bf(a1 * d) << 16);
    *(unsigned*)(hs + (size_t)r * 64 + c2) = pk;
  }
}

// ---------------- layer-2 linear: hs2[N,128](bf16) = (xin[N,64](bf16) @ W[64,128]) * dis[row] ----------------
__global__ __launch_bounds__(256) void k_lin64x128(const unsigned short* __restrict__ xin, const float* __restrict__ W,
                                                   const float* __restrict__ dis, unsigned short* __restrict__ hs, int N) {
  __shared__ float Ws[64 * 128];
  __shared__ float xs[8][64];
  int t = threadIdx.x;
  for (int j = t; j < 64 * 128; j += 256) Ws[j] = W[j];
  int r0 = blockIdx.x * 8;
  for (int j = t; j < 8 * 64; j += 256) {
    int r = j >> 6, k = j & 63;
    int gr = r0 + r;
    xs[r][k] = (gr < N) ? bf2f(xin[(size_t)gr * 64 + k]) : 0.f;
  }
  __syncthreads();
  int c = t & 127;
  int rb = (t >> 7) * 4;
  float acc[4] = {0.f, 0.f, 0.f, 0.f};
  for (int k = 0; k < 64; k++) {
    float w = Ws[k * 128 + c];
#pragma unroll
    for (int rr = 0; rr < 4; rr++) acc[rr] = fmaf(xs[rb + rr][k], w, acc[rr]);
  }
#pragma unroll
  for (int rr = 0; rr < 4; rr++) {
    int gr = r0 + rb + rr;
    if (gr < N) hs[(size_t)gr * 128 + c] = f2bf(acc[rr] * dis[gr]);
  }
}

// ---------------- aggregation (bf16 in, bf16 out): out[c] = relu(dis[c]*(hs[c]+sum hs[r]) + b) ----------------
template <int F>
__global__ __launch_bounds__(256) void k_agg_bf(const unsigned short* __restrict__ hs,
                                                const int* __restrict__ starts, const int* __restrict__ cnt,
                                                const int* __restrict__ srow, const float* __restrict__ dis,
                                                const float* __restrict__ b, unsigned short* __restrict__ out, int N) {
  constexpr int LPN = F / 2;  // lanes per node, each lane does 2 features
  int t = threadIdx.x;
  int c = blockIdx.x * (256 / LPN) + t / LPN;
  if (c >= N) return;
  int fi = (t % LPN) * 2;
  unsigned v = *(const unsigned*)(hs + (size_t)c * F + fi);
  float ax = bflo(v), ay = bfhi(v);
  int s0 = starts[c], n = cnt[c];
  const int* sp = srow + s0;
  int e = 0;
  for (; e + 4 <= n; e += 4) {
    int r0 = sp[e], r1 = sp[e + 1], r2 = sp[e + 2], r3 = sp[e + 3];
    unsigned v0 = *(const unsigned*)(hs + (size_t)r0 * F + fi);
    unsigned v1 = *(const unsigned*)(hs + (size_t)r1 * F + fi);
    unsigned v2 = *(const unsigned*)(hs + (size_t)r2 * F + fi);
    unsigned v3 = *(const unsigned*)(hs + (size_t)r3 * F + fi);
    ax += bflo(v0) + bflo(v1) + bflo(v2) + bflo(v3);
    ay += bfhi(v0) + bfhi(v1) + bfhi(v2) + bfhi(v3);
  }
  for (; e < n; e++) {
    unsigned vv = *(const unsigned*)(hs + (size_t)sp[e] * F + fi);
    ax += bflo(vv);
    ay += bfhi(vv);
  }
  float d = dis[c];
  float ox = fmaxf(fmaf(d, ax, b[fi]), 0.f);
  float oy = fmaxf(fmaf(d, ay, b[fi + 1]), 0.f);
  *(unsigned*)(out + (size_t)c * F + fi) = (unsigned)f2bf(ox) | ((unsigned)f2bf(oy) << 16);
}

// ---------------- B-operand fragment packers (layout: frag=(k/32)*8+(n/16), lane=(n&15)|(((k>>3)&3)<<4), j=k&7) ----
__global__ void k_pack_b_bf16src(const unsigned short* __restrict__ src, short* __restrict__ dst, int K) {
  int e = blockIdx.x * 256 + threadIdx.x;
  if (e >= K * 128) return;
  int k = e >> 7, n = e & 127;
  int frag = (k >> 5) * 8 + (n >> 4);
  int l = (n & 15) | (((k >> 3) & 3) << 4);
  int j = k & 7;
  dst[(size_t)frag * 512 + l * 8 + j] = (short)src[e];
}
__global__ void k_pack_b_f32src(const float* __restrict__ src, short* __restrict__ dst, int K) {
  int e = blockIdx.x * 256 + threadIdx.x;
  if (e >= K * 128) return;
  int k = e >> 7, n = e & 127;
  int frag = (k >> 5) * 8 + (n >> 4);
  int l = (n & 15) | (((k >> 3) & 3) << 4);
  int j = k & 7;
  dst[(size_t)frag * 512 + l * 8 + j] = (short)f2bf(src[e]);
}

__device__ __forceinline__ short8 zero8() {
  short8 z;
#pragma unroll
  for (int j = 0; j < 8; j++) z[j] = 0;
  return z;
}

__device__ __forceinline__ short8 load_a_f32(const float* p, bool ok) {
  short8 r;
  if (ok) {
    float4 v0 = *(const float4*)p;
    float4 v1 = *(const float4*)(p + 4);
    r[0] = (short)f2bf(v0.x); r[1] = (short)f2bf(v0.y); r[2] = (short)f2bf(v0.z); r[3] = (short)f2bf(v0.w);
    r[4] = (short)f2bf(v1.x); r[5] = (short)f2bf(v1.y); r[6] = (short)f2bf(v1.z); r[7] = (short)f2bf(v1.w);
  } else {
    r = zero8();
  }
  return r;
}

// ---------------- GEMM1 (MFMA): xcdec[M,128](bf16) = Q[M,512](fp32) @ Bq ----------------
__global__ __launch_bounds__(256) void k_gemm_q_mfma(const float* __restrict__ Q, const short* __restrict__ Bp,
                                                     unsigned short* __restrict__ outb, int M) {
  int t = threadIdx.x;
  int lane = t & 63;
  int wid = t >> 6;
  int m0 = blockIdx.x * 128 + wid * 32;
  int mrow = lane & 15;
  int kg = lane >> 4;  // 0..3
  f32x4 acc[2][8];
#pragma unroll
  for (int mi = 0; mi < 2; mi++)
#pragma unroll
    for (int nf = 0; nf < 8; nf++) acc[mi][nf] = (f32x4){0.f, 0.f, 0.f, 0.f};
  int r0 = m0 + mrow, r1 = m0 + 16 + mrow;
  bool ok0 = r0 < M, ok1 = r1 < M;
  const float* a0p = Q + (size_t)r0 * 512 + kg * 8;
  const float* a1p = Q + (size_t)r1 * 512 + kg * 8;
  const short* bl = Bp + lane * 8;
  for (int ks = 0; ks < 16; ks++) {
    short8 a0 = load_a_f32(a0p + ks * 32, ok0);
    short8 a1 = load_a_f32(a1p + ks * 32, ok1);
    const short* bb = bl + (ks << 12);
#pragma unroll
    for (int nf = 0; nf < 8; nf++) {
      short8 b = *(const short8*)(bb + (nf << 9));
      acc[0][nf] = __builtin_amdgcn_mfma_f32_16x16x32_bf16(a0, b, acc[0][nf], 0, 0, 0);
      acc[1][nf] = __builtin_amdgcn_mfma_f32_16x16x32_bf16(a1, b, acc[1][nf], 0, 0, 0);
    }
  }
  int col = lane & 15;
  int g = lane >> 4;
#pragma unroll
  for (int mi = 0; mi < 2; mi++)
#pragma unroll
    for (int nf = 0; nf < 8; nf++)
#pragma unroll
      for (int r = 0; r < 4; r++) {
        int row = m0 + mi * 16 + g * 4 + r;
        if (row < M) outb[(size_t)row * 128 + nf * 16 + col] = f2bf(acc[mi][nf][r]);
      }
}

// ---------------- GEMM2 (MFMA) + gate epilogue ----------------
__global__ __launch_bounds__(256) void k_gemm_fuse_mfma(const unsigned short* __restrict__ Xs,
                                                        const unsigned short* __restrict__ Xc,
                                                        const short* __restrict__ A1p, const float* __restrict__ ab1,
                                                        const float* __restrict__ A2, const float* __restrict__ ab2,
                                                        float* __restrict__ fused, int M) {
  int t = threadIdx.x;
  int lane = t & 63;
  int wid = t >> 6;
  int m0 = blockIdx.x * 128 + wid * 32;
  int mrow = lane & 15;
  int kg = lane >> 4;
  f32x4 acc[2][8];
#pragma unroll
  for (int mi = 0; mi < 2; mi++)
#pragma unroll
    for (int nf = 0; nf < 8; nf++) acc[mi][nf] = (f32x4){0.f, 0.f, 0.f, 0.f};
  int r0 = m0 + mrow, r1 = m0 + 16 + mrow;
  bool ok0 = r0 < M, ok1 = r1 < M;
  const short* bl = A1p + lane * 8;
  for (int ks = 0; ks < 8; ks++) {
    const unsigned short* src = (ks < 4) ? Xs : Xc;
    int kb = (ks & 3) * 32 + kg * 8;
    short8 a0 = ok0 ? *(const short8*)(src + (size_t)r0 * 128 + kb) : zero8();
    short8 a1 = ok1 ? *(const short8*)(src + (size_t)r1 * 128 + kb) : zero8();
    const short* bb = bl + (ks << 12);
#pragma unroll
    for (int nf = 0; nf < 8; nf++) {
      short8 b = *(const short8*)(bb + (nf << 9));
      acc[0][nf] = __builtin_amdgcn_mfma_f32_16x16x32_bf16(a0, b, acc[0][nf], 0, 0, 0);
      acc[1][nf] = __builtin_amdgcn_mfma_f32_16x16x32_bf16(a1, b, acc[1][nf], 0, 0, 0);
    }
  }
  int col16 = lane & 15;
  int g = lane >> 4;
  float bias[8], w20[8], w21[8];
#pragma unroll
  for (int nf = 0; nf < 8; nf++) {
    int cc = nf * 16 + col16;
    bias[nf] = ab1[cc];
    w20[nf] = A2[2 * cc];
    w21[nf] = A2[2 * cc + 1];
  }
  float b20 = ab2[0], b21 = ab2[1];
#pragma unroll
  for (int mi = 0; mi < 2; mi++) {
#pragma unroll
    for (int r = 0; r < 4; r++) {
      float u0 = 0.f, u1 = 0.f;
#pragma unroll
      for (int nf = 0; nf < 8; nf++) {
        float tv = fmaxf(acc[mi][nf][r] + bias[nf], 0.f);
        u0 = fmaf(tv, w20[nf], u0);
        u1 = fmaf(tv, w21[nf], u1);
      }
#pragma unroll
      for (int off = 1; off < 16; off <<= 1) {
        u0 += __shfl_xor(u0, off);
        u1 += __shfl_xor(u1, off);
      }
      int row = m0 + mi * 16 + g * 4 + r;
      if (row < M) {
        float ua = u0 + b20, ub = u1 + b21;
        float mx = fmaxf(ua, ub);
        float e0 = __expf(ua - mx), e1 = __expf(ub - mx);
        float inv = 1.f / (e0 + e1);
        float w0 = e0 * inv, w1 = e1 * inv;
        int p = col16;  // each of the 16 lanes in this group writes 8 cols of this row
        const unsigned short* xsp = Xs + (size_t)row * 128 + p * 8;
        const unsigned short* xcp = Xc + (size_t)row * 128 + p * 8;
        float* op = fused + (size_t)row * 128 + p * 8;
        float4 o0, o1;
        unsigned sx0 = *(const unsigned*)(xsp + 0), sx1 = *(const unsigned*)(xsp + 2);
        unsigned sx2 = *(const unsigned*)(xsp + 4), sx3 = *(const unsigned*)(xsp + 6);
        unsigned cx0 = *(const unsigned*)(xcp + 0), cx1 = *(const unsigned*)(xcp + 2);
        unsigned cx2 = *(const unsigned*)(xcp + 4), cx3 = *(const unsigned*)(xcp + 6);
        o0.x = w0 * bflo(sx0) + w1 * bflo(cx0);
        o0.y = w0 * bfhi(sx0) + w1 * bfhi(cx0);
        o0.z = w0 * bflo(sx1) + w1 * bflo(cx1);
        o0.w = w0 * bfhi(sx1) + w1 * bfhi(cx1);
        o1.x = w0 * bflo(sx2) + w1 * bflo(cx2);
        o1.y = w0 * bfhi(sx2) + w1 * bfhi(cx2);
        o1.z = w0 * bflo(sx3) + w1 * bflo(cx3);
        o1.w = w0 * bfhi(sx3) + w1 * bfhi(cx3);
        *(float4*)op = o0;
        *(float4*)(op + 4) = o1;
      }
    }
  }
}

// ---------------- heads: class = fused@Wcls+bcls ; dom = relu(fused@D1+db1)@D2+db2 ----------------
__global__ __launch_bounds__(256) void k_final(const float* __restrict__ fused, const float* __restrict__ Wcls,
                                               const float* __restrict__ bcls, const float* __restrict__ D1,
                                               const float* __restrict__ db1, const float* __restrict__ D2,
                                               const float* __restrict__ db2, float* __restrict__ cls_out,
                                               float* __restrict__ dom_out, int M) {
  __shared__ float D1s[128 * 64];
  __shared__ float Ws[128 * 9];
  __shared__ float D2s[64 * 2];
  __shared__ float fr[16][128];
  __shared__ float hh[16][64];
  int t = threadIdx.x;
  for (int j = t; j < 128 * 64; j += 256) D1s[j] = D1[j];
  for (int j = t; j < 128 * 9; j += 256) Ws[j] = Wcls[j];
  if (t < 128) D2s[t] = D2[t];
  int r0 = blockIdx.x * 16;
  for (int j = t; j < 16 * 128; j += 256) {
    int r = j >> 7, k = j & 127;
    int gr = r0 + r;
    fr[r][k] = (gr < M) ? fused[(size_t)gr * 128 + k] : 0.f;
  }
  __syncthreads();
#pragma unroll
  for (int q = 0; q < 4; q++) {
    int j = t + q * 256;
    int r = j >> 6, h = j & 63;
    float a = db1[h];
    for (int k = 0; k < 128; k++) a = fmaf(fr[r][k], D1s[k * 64 + h], a);
    hh[r][h] = fmaxf(a, 0.f);
  }
  if (t < 144) {
    int r = t / 9, c = t % 9;
    float a = bcls[c];
    for (int k = 0; k < 128; k++) a = fmaf(fr[r][k], Ws[k * 9 + c], a);
    int gr = r0 + r;
    if (gr < M) cls_out[(size_t)gr * 9 + c] = a;
  }
  __syncthreads();
  if (t < 32) {
    int r = t >> 1, j = t & 1;
    float a = db2[j];
    for (int h = 0; h < 64; h++) a = fmaf(hh[r][h], D2s[h * 2 + j], a);
    int gr = r0 + r;
    if (gr < M) dom_out[(size_t)gr * 2 + j] = a;
  }
}

extern "C" void kernel_launch(void* const* d_in, const int* in_sizes, int n_in,
                              void* d_out, int out_size, void* d_ws, size_t ws_size,
                              hipStream_t stream) {
  const float* x_s = (const float*)d_in[0];
  const float* x_c = (const float*)d_in[1];
  const float* Q = (const float*)d_in[2];
  const int* eis = (const int*)d_in[3];
  const int* eic = (const int*)d_in[4];
  const float* W1s = (const float*)d_in[5];
  const float* b1s = (const float*)d_in[6];
  const float* W2s = (const float*)d_in[7];
  const float* b2s = (const float*)d_in[8];
  const float* W1c = (const float*)d_in[9];
  const float* b1c = (const float*)d_in[10];
  const float* W2c = (const float*)d_in[11];
  const float* b2c = (const float*)d_in[12];
  const float* A1 = (const float*)d_in[13];
  const float* ab1 = (const float*)d_in[14];
  const float* A2 = (const float*)d_in[15];
  const float* ab2 = (const float*)d_in[16];
  const float* Wcls = (const float*)d_in[17];
  const float* bcls = (const float*)d_in[18];
  const float* D1 = (const float*)d_in[19];
  const float* db1 = (const float*)d_in[20];
  const float* D2 = (const float*)d_in[21];
  const float* db2 = (const float*)d_in[22];

  float* out_cls = (float*)d_out;
  float* out_dom = out_cls + (size_t)kNS * 9;
  float* out_fus = out_dom + (size_t)kNS * 2;

  char* p = (char*)d_ws;
  auto alloc = [&](size_t bytes) -> void* {
    void* r = (void*)p;
    p += (bytes + 255) & ~(size_t)255;
    return r;
  };
  int* deg_s = (int*)alloc((size_t)kNS * 4);
  int* starts_s = (int*)alloc((size_t)kNS * 4);
  int* cursor_s = (int*)alloc((size_t)kNS * 4);
  int* bsum_s = (int*)alloc(512 * 4);
  float* dis_s = (float*)alloc((size_t)kNS * 4);
  int* srow_s = (int*)alloc((size_t)kES * 4);
  int* deg_c = (int*)alloc((size_t)kNC * 4);
  int* starts_c = (int*)alloc((size_t)kNC * 4);
  int* cursor_c = (int*)alloc((size_t)kNC * 4);
  int* bsum_c = (int*)alloc(512 * 4);
  float* dis_c = (float*)alloc((size_t)kNC * 4);
  int* srow_c = (int*)alloc((size_t)kEC * 4);
  unsigned short* hc1b = (unsigned short*)alloc((size_t)kNC * 64 * 2);
  unsigned short* xc1b = (unsigned short*)alloc((size_t)kNC * 64 * 2);
  unsigned short* hc2b = (unsigned short*)alloc((size_t)kNC * 128 * 2);
  unsigned short* xc2b = (unsigned short*)alloc((size_t)kNC * 128 * 2);
  unsigned short* hs1b = (unsigned short*)alloc((size_t)kNS * 64 * 2);
  unsigned short* xs1b = (unsigned short*)alloc((size_t)kNS * 64 * 2);
  unsigned short* hs2b = (unsigned short*)alloc((size_t)kNS * 128 * 2);
  unsigned short* xs2b = (unsigned short*)alloc((size_t)kNS * 128 * 2);
  unsigned short* xcdb = (unsigned short*)alloc((size_t)kNS * 128 * 2);
  short* Bq = (short*)alloc((size_t)512 * 128 * 2);
  short* A1p = (short*)alloc((size_t)256 * 128 * 2);
  (void)ws_size; (void)in_sizes; (void)n_in; (void)out_size;

  hipMemsetAsync(deg_s, 0, (size_t)kNS * 4, stream);
  hipMemsetAsync(deg_c, 0, (size_t)kNC * 4, stream);

  const int nbS = (kNS + 255) / 256;
  const int nbC = (kNC + 255) / 256;

  // sample-graph CSR
  k_hist<<<(kES + 255) / 256, 256, 0, stream>>>(eis + kES, kES, deg_s);
  k_dis<<<nbS, 256, 0, stream>>>(deg_s, kNS, dis_s);
  k_scan1<<<nbS, 256, 0, stream>>>(deg_s, kNS, starts_s, bsum_s);
  k_scan2<<<1, 256, 0, stream>>>(bsum_s, nbS);
  k_scan3<<<nbS, 256, 0, stream>>>(starts_s, cursor_s, bsum_s, kNS);
  k_scatter<<<(kES + 255) / 256, 256, 0, stream>>>(eis, eis + kES, kES, cursor_s, srow_s);

  // cluster-graph CSR
  k_hist<<<(kEC + 255) / 256, 256, 0, stream>>>(eic + kEC, kEC, deg_c);
  k_dis<<<nbC, 256, 0, stream>>>(deg_c, kNC, dis_c);
  k_scan1<<<nbC, 256, 0, stream>>>(deg_c, kNC, starts_c, bsum_c);
  k_scan2<<<1, 256, 0, stream>>>(bsum_c, nbC);
  k_scan3<<<nbC, 256, 0, stream>>>(starts_c, cursor_c, bsum_c, kNC);
  k_scatter<<<(kEC + 255) / 256, 256, 0, stream>>>(eic, eic + kEC, kEC, cursor_c, srow_c);

  // pack A1 (independent)
  k_pack_b_f32src<<<(256 * 128 + 255) / 256, 256, 0, stream>>>(A1, A1p, 256);

  // cluster branch
  k_lin7<<<(kNC * 32 + 255) / 256, 256, 0, stream>>>(x_c, W1c, dis_c, hc1b, kNC);
  k_agg_bf<64><<<(kNC + 7) / 8, 256, 0, stream>>>(hc1b, starts_c, deg_c, srow_c, dis_c, b1c, xc1b, kNC);
  k_lin64x128<<<(kNC + 7) / 8, 256, 0, stream>>>(xc1b, W2c, dis_c, hc2b, kNC);
  k_agg_bf<128><<<(kNC + 3) / 4, 256, 0, stream>>>(hc2b, starts_c, deg_c, srow_c, dis_c, b2c, xc2b, kNC);
  k_pack_b_bf16src<<<(512 * 128 + 255) / 256, 256, 0, stream>>>(xc2b, Bq, 512);

  // sample branch
  k_lin7<<<(kNS * 32 + 255) / 256, 256, 0, stream>>>(x_s, W1s, dis_s, hs1b, kNS);
  k_agg_bf<64><<<(kNS + 7) / 8, 256, 0, stream>>>(hs1b, starts_s, deg_s, srow_s, dis_s, b1s, xs1b, kNS);
  k_lin64x128<<<(kNS + 7) / 8, 256, 0, stream>>>(xs1b, W2s, dis_s, hs2b, kNS);
  k_agg_bf<128><<<(kNS + 3) / 4, 256, 0, stream>>>(hs2b, starts_s, deg_s, srow_s, dis_s, b2s, xs2b, kNS);

  // decode + fusion gate + heads
  k_gemm_q_mfma<<<(kNS + 127) / 128, 256, 0, stream>>>(Q, Bq, xcdb, kNS);
  k_gemm_fuse_mfma<<<(kNS + 127) / 128, 256, 0, stream>>>(xs2b, xcdb, A1p, ab1, A2, ab2, out_fus, kNS);
  k_final<<<(kNS + 15) / 16, 256, 0, stream>>>(out_fus, Wcls, bcls, D1, db1, D2, db2, out_cls, out_dom, kNS);
}